// Round 12
// baseline (279.109 us; speedup 1.0000x reference)
//
#include <hip/hip_runtime.h>
#include <hip/hip_bf16.h>

#define DEVI __device__ __forceinline__

constexpr int Bc = 2, Cc = 64, Tc = 4, Hc = 64, Wc = 64, OFFc = 54, KVc = 27;
constexpr int HW  = Hc * Wc;     // 4096
constexpr int THW = Tc * HW;     // 16384

typedef __attribute__((ext_vector_type(8))) short bf16x8;
typedef __attribute__((ext_vector_type(4))) float f32x4;

DEVI short f2bf(float f) {
    __hip_bfloat16 h = __float2bfloat16(f);
    return *reinterpret_cast<short*>(&h);
}
DEVI float bf2f(short s) {
    unsigned u = ((unsigned)(unsigned short)s) << 16;
    float f; __builtin_memcpy(&f, &u, 4); return f;
}

// ------- weights -> K-major MFMA A layout -------
__global__ __launch_bounds__(256) void w_prep(const float* __restrict__ w,
                                              __hip_bfloat16* __restrict__ wAk, int ovalid) {
    int i = blockIdx.x * 256 + threadIdx.x;   // 216*512 = 110592
    if (i >= 216 * 512) return;
    int u = i >> 9, r = i & 511;
    int mf = u & 3, ch = (u >> 2) & 1, tap = u >> 3;
    int o = mf * 16 + (r >> 5), c = ch * 32 + (r & 31);
    float v = (o < ovalid) ? w[(o * Cc + c) * KVc + tap] : 0.f;
    wAk[i] = __float2bfloat16(v);
}

// ------- cast + transpose to channel-last bf16 -------
__global__ __launch_bounds__(256) void cast_cl(const float* __restrict__ x,
                                               __hip_bfloat16* __restrict__ xcl) {
    __shared__ float s[64][65];
    int tid = threadIdx.x;
    int bi  = blockIdx.x;
    int h = bi & 63, t = (bi >> 6) & 3, b = bi >> 8;

    const float* xp = x + (size_t)b * Cc * THW + t * HW + h * 64;
    int w0 = tid & 63, c0 = tid >> 6;
    #pragma unroll
    for (int i = 0; i < 16; ++i) {
        int c = c0 + i * 4;
        s[c][w0] = xp[(size_t)c * THW + w0];
    }
    __syncthreads();

    __hip_bfloat16* dst = xcl + (((size_t)b * Tc + t) * HW + (size_t)h * 64) * 64;
    #pragma unroll
    for (int r = 0; r < 2; ++r) {
        int j  = tid + r * 256;
        int w  = j >> 3;
        int c8 = j & 7;
        bf16x8 v;
        #pragma unroll
        for (int jj = 0; jj < 8; ++jj)
            v[jj] = f2bf(s[c8 * 8 + jj][w]);
        *reinterpret_cast<bf16x8*>(dst + w * 64 + c8 * 8) = v;
    }
}

// ================= fused offset-conv + deformable-conv =================
// block = (b,t,h) full row, 512 thr = 8 waves = np(2 pos-pairs) x chh(2) x par(2 tap-parity).
// Pass A (offset conv) reads GLOBAL directly (aligned, coalesced), accumulates into
// f32 reduce buffer aliased on the tile region, converts once to f16 s_off.
// Pass B stages 5-row tile per kt (swizzled) and samples via ds_read_b128.
// Each af weight-fragment load feeds 2 MFMAs (np pair); tap-parity halves per-wave chains.
// LDS 47KB -> 3 blocks/CU. Plane->XCD: pid = blockIdx&7 (R10-validated, ~11MB FETCH).
template <bool L2>
__global__ __launch_bounds__(512, 4) void fused_deform(
    const __hip_bfloat16* __restrict__ src, const __hip_bfloat16* __restrict__ owAk,
    const float* __restrict__ obias, const __hip_bfloat16* __restrict__ wAk,
    const float* __restrict__ xres, float* __restrict__ outf,
    __hip_bfloat16* __restrict__ ycl)
{
    __shared__ __align__(16) char s_mem[40960 + 7168];
    short*    s_tile = (short*)s_mem;                  // [5][64 w][64 c] bf16, swizzled
    float*    s_redA = (float*)s_mem;                  // pass A reduce [54][68] f32 (aliased)
    float*    s_red  = (float*)s_mem;                  // final reduce [64][68] f32 (aliased)
    _Float16* s_off  = (_Float16*)(s_mem + 40960);     // [54][66] f16 offsets

    int tid = threadIdx.x;
    int wv = tid >> 6, lane = tid & 63, l15 = lane & 15, l4 = lane >> 4;
    int par = wv & 1, chh = (wv >> 1) & 1, np = wv >> 2;
    int bi = blockIdx.x;
    int pid = bi & 7, h = bi >> 3;       // plane -> XCD via %8 round-robin
    int b = pid >> 2, t = pid & 3;

    int p1 = np * 32 + l15, p2 = p1 + 16;   // this wave's two position groups
    int cbase = chh * 32 + l4 * 8;          // channel slice (MFMA K slice)
    int ktlo = (t == 0) ? 1 : 0, kthi = (t == 3) ? 2 : 3;

    const __hip_bfloat16* xb = src + ((size_t)b << 20);

    // ---- init pass-A reduce buffer with bias ----
    for (int i = tid; i < OFFc * 68; i += 512) {
        int o = i / 68, c = i - o * 68;
        s_redA[i] = (c < 64) ? obias[o] : 0.f;
    }
    __syncthreads();

    // ================= pass A: offset conv (B from GLOBAL, no barriers) =================
    {
        f32x4 cacc[2][4];
        #pragma unroll
        for (int q = 0; q < 2; ++q)
            #pragma unroll
            for (int mf = 0; mf < 4; ++mf) cacc[q][mf] = (f32x4){0.f, 0.f, 0.f, 0.f};

        for (int kt = ktlo; kt < kthi; ++kt) {
            int tt = t + kt - 1;
            const __hip_bfloat16* xt = xb + ((size_t)tt << 18);
            for (int rr = par; rr < 9; rr += 2) {
                int kh = rr / 3, kw = rr - kh * 3, tap = kt * 9 + rr;
                int hh = h + kh - 1;
                bool rowok = (unsigned)hh < 64u;
                const __hip_bfloat16* xrow = xt + ((hh * 64) << 6) + cbase;
                int ws1 = p1 + kw - 1, ws2 = p2 + kw - 1;
                bf16x8 bv1 = {0, 0, 0, 0, 0, 0, 0, 0}, bv2 = bv1;
                if (rowok && (unsigned)ws1 < 64u) bv1 = *reinterpret_cast<const bf16x8*>(xrow + (ws1 << 6));
                if (rowok && (unsigned)ws2 < 64u) bv2 = *reinterpret_cast<const bf16x8*>(xrow + (ws2 << 6));
                const __hip_bfloat16* ab = owAk + ((tap * 2 + chh) << 11) + (l15 << 5) + (l4 << 3);
                #pragma unroll
                for (int mf = 0; mf < 4; ++mf) {
                    bf16x8 af = *reinterpret_cast<const bf16x8*>(ab + (mf << 9));
                    cacc[0][mf] = __builtin_amdgcn_mfma_f32_16x16x32_bf16(af, bv1, cacc[0][mf], 0, 0, 0);
                    cacc[1][mf] = __builtin_amdgcn_mfma_f32_16x16x32_bf16(af, bv2, cacc[1][mf], 0, 0, 0);
                }
            }
        }
        #pragma unroll
        for (int q = 0; q < 2; ++q) {
            int pp = q ? p2 : p1;
            #pragma unroll
            for (int mf = 0; mf < 4; ++mf)
                #pragma unroll
                for (int jj = 0; jj < 4; ++jj) {
                    int o = mf * 16 + l4 * 4 + jj;
                    if (o < OFFc) atomicAdd(&s_redA[o * 68 + pp], cacc[q][mf][jj]);
                }
        }
    }
    __syncthreads();

    // ---- convert reduce -> f16 s_off ----
    for (int i = tid; i < OFFc * 64; i += 512) {
        int o = i >> 6, pp = i & 63;
        s_off[o * 66 + pp] = (_Float16)s_redA[o * 68 + pp];
    }
    __syncthreads();

    // ================= pass B: deformable conv (LDS tile) =================
    int wst = tid >> 3, sst = tid & 7;   // staging lane coords

    auto stage_load = [&](int kt, bf16x8 (&reg)[5]) {
        int tt = t + kt - 1;
        const __hip_bfloat16* xt = xb + ((size_t)tt << 18);
        #pragma unroll
        for (int r = 0; r < 5; ++r) {
            int hh = h - 2 + r;
            bf16x8 v = {0, 0, 0, 0, 0, 0, 0, 0};
            if ((unsigned)hh < 64u)
                v = *reinterpret_cast<const bf16x8*>(xt + ((hh * 64 + wst) << 6) + sst * 8);
            reg[r] = v;
        }
    };
    auto stage_write = [&](bf16x8 (&reg)[5]) {
        #pragma unroll
        for (int r = 0; r < 5; ++r) {
            int byte = (r * 8192 + wst * 128 + sst * 16) ^ ((wst & 7) << 4);
            *reinterpret_cast<bf16x8*>((char*)s_tile + byte) = reg[r];
        }
    };
    auto ldread = [&](int sl, int w) -> bf16x8 {
        int byte = (sl * 8192 + w * 128 + cbase * 2) ^ ((w & 7) << 4);
        return *reinterpret_cast<const bf16x8*>((const char*)s_tile + byte);
    };

    f32x4 dacc[2][4];
    #pragma unroll
    for (int q = 0; q < 2; ++q)
        #pragma unroll
        for (int mf = 0; mf < 4; ++mf) dacc[q][mf] = (f32x4){0.f, 0.f, 0.f, 0.f};

    {
        bf16x8 streg[5];
        stage_load(ktlo, streg);
        for (int kt = ktlo; kt < kthi; ++kt) {
            __syncthreads();              // prior reads of tile region done
            stage_write(streg);
            __syncthreads();
            if (kt + 1 < kthi) stage_load(kt + 1, streg);

            int tt = t + kt - 1;
            const __hip_bfloat16* xt = xb + ((size_t)tt << 18);
            for (int rr = par; rr < 9; rr += 2) {
                int kh = rr / 3, kw = rr - kh * 3, tap = kt * 9 + rr;
                const __hip_bfloat16* ab = wAk + ((tap * 2 + chh) << 11) + (l15 << 5) + (l4 << 3);
                bf16x8 af[4];
                #pragma unroll
                for (int mf = 0; mf < 4; ++mf)
                    af[mf] = *reinterpret_cast<const bf16x8*>(ab + (mf << 9));

                #pragma unroll
                for (int q = 0; q < 2; ++q) {
                    int pp = q ? p2 : p1;
                    float dh = (float)s_off[(tap * 2 + 0) * 66 + pp];
                    float dw = (float)s_off[(tap * 2 + 1) * 66 + pp];
                    float hs  = (float)(h + kh - 1) + dh;
                    float wsf = (float)(pp + kw - 1) + dw;
                    float fh = floorf(hs), fw = floorf(wsf);
                    int h0 = (int)fh, w0 = (int)fw;
                    float lh = hs - fh, lw = wsf - fw;
                    float q0 = (1.f - lw) * (((unsigned)w0 < 64u) ? 1.f : 0.f);
                    float q1 = lw         * (((unsigned)(w0 + 1) < 64u) ? 1.f : 0.f);
                    int wc0 = min(max(w0, 0), 63), wc1 = min(max(w0 + 1, 0), 63);
                    int r0 = h0 - (h - 2);
                    int r0c = min(max(r0, 0), 3);
                    float cf0, cf1, cf2, cf3;
                    bf16x8 g0 = ldread(r0c, wc0),     g1 = ldread(r0c, wc1);
                    bf16x8 g2 = ldread(r0c + 1, wc0), g3 = ldread(r0c + 1, wc1);
                    bool bad = (r0 < 0) | (r0 > 3);
                    if (__any((int)bad)) {
                        // exact global fallback (|dh| >= 1; ~never taken)
                        float u0 = (1.f - lh) * (((unsigned)h0 < 64u) ? 1.f : 0.f);
                        float u1 = lh         * (((unsigned)(h0 + 1) < 64u) ? 1.f : 0.f);
                        cf0 = u0 * q0; cf1 = u0 * q1; cf2 = u1 * q0; cf3 = u1 * q1;
                        int hc0 = min(max(h0, 0), 63), hc1 = min(max(h0 + 1, 0), 63);
                        g0 = *reinterpret_cast<const bf16x8*>(xt + ((hc0 * 64 + wc0) << 6) + cbase);
                        g1 = *reinterpret_cast<const bf16x8*>(xt + ((hc0 * 64 + wc1) << 6) + cbase);
                        g2 = *reinterpret_cast<const bf16x8*>(xt + ((hc1 * 64 + wc0) << 6) + cbase);
                        g3 = *reinterpret_cast<const bf16x8*>(xt + ((hc1 * 64 + wc1) << 6) + cbase);
                    } else {
                        cf0 = (1.f - lh) * q0; cf1 = (1.f - lh) * q1;
                        cf2 = lh * q0;         cf3 = lh * q1;
                    }
                    bf16x8 bfrag;
                    #pragma unroll
                    for (int jj = 0; jj < 8; ++jj) {
                        float s = cf0 * bf2f(g0[jj]) + cf1 * bf2f(g1[jj])
                                + cf2 * bf2f(g2[jj]) + cf3 * bf2f(g3[jj]);
                        bfrag[jj] = f2bf(s);
                    }
                    #pragma unroll
                    for (int mf = 0; mf < 4; ++mf)
                        dacc[q][mf] = __builtin_amdgcn_mfma_f32_16x16x32_bf16(af[mf], bfrag, dacc[q][mf], 0, 0, 0);
                }
            }
        }
    }

    // ---- final reduce: s_red aliased onto tile ----
    __syncthreads();
    for (int i = tid; i < 64 * 68; i += 512) s_red[i] = 0.f;
    __syncthreads();
    #pragma unroll
    for (int q = 0; q < 2; ++q) {
        int pp = q ? p2 : p1;
        #pragma unroll
        for (int mf = 0; mf < 4; ++mf)
            #pragma unroll
            for (int jj = 0; jj < 4; ++jj) {
                int o = mf * 16 + l4 * 4 + jj;
                atomicAdd(&s_red[pp * 68 + o], dacc[q][mf][jj]);
            }
    }
    __syncthreads();

    // ---- fused epilogue ----
    if (!L2) {
        int pp = tid >> 3, o8 = (tid & 7) << 3;
        __hip_bfloat16* dst = ycl + ((((size_t)b * Tc + t) * HW + h * 64 + pp) << 6) + o8;
        bf16x8 o8v;
        #pragma unroll
        for (int jj = 0; jj < 8; ++jj) {
            float v = s_red[pp * 68 + o8 + jj];
            v = v >= 0.f ? v : 0.1f * v;
            o8v[jj] = f2bf(v);
        }
        *reinterpret_cast<bf16x8*>(dst) = o8v;
    } else {
        int o = tid >> 3, pg = (tid & 7) << 3;
        size_t base = ((size_t)(b * Cc + o) * Tc + t) * HW + h * 64 + pg;
        #pragma unroll
        for (int q = 0; q < 2; ++q) {
            f32x4 r, xv = *reinterpret_cast<const f32x4*>(xres + base + q * 4);
            #pragma unroll
            for (int jj = 0; jj < 4; ++jj) r[jj] = s_red[(pg + q * 4 + jj) * 68 + o] + xv[jj];
            *reinterpret_cast<f32x4*>(outf + base + q * 4) = r;
        }
    }
}

extern "C" void kernel_launch(void* const* d_in, const int* in_sizes, int n_in,
                              void* d_out, int out_size, void* d_ws, size_t ws_size,
                              hipStream_t stream)
{
    const float* x   = (const float*)d_in[0];
    const float* w0  = (const float*)d_in[1];
    const float* ow0 = (const float*)d_in[2];
    const float* ob0 = (const float*)d_in[3];
    const float* w1  = (const float*)d_in[4];
    const float* ow1 = (const float*)d_in[5];
    const float* ob1 = (const float*)d_in[6];
    float* out = (float*)d_out;

    __hip_bfloat16* xcl  = (__hip_bfloat16*)d_ws;
    __hip_bfloat16* ycl  = xcl  + (size_t)Bc * THW * 64;
    __hip_bfloat16* owA0 = ycl  + (size_t)Bc * THW * 64;
    __hip_bfloat16* owA1 = owA0 + (size_t)216 * 512;
    __hip_bfloat16* wA0  = owA1 + (size_t)216 * 512;
    __hip_bfloat16* wA1  = wA0  + (size_t)216 * 512;

    w_prep<<<432, 256, 0, stream>>>(ow0, owA0, OFFc);
    w_prep<<<432, 256, 0, stream>>>(ow1, owA1, OFFc);
    w_prep<<<432, 256, 0, stream>>>(w0,  wA0,  Cc);
    w_prep<<<432, 256, 0, stream>>>(w1,  wA1,  Cc);
    cast_cl<<<512, 256, 0, stream>>>(x, xcl);

    fused_deform<false><<<512, 512, 0, stream>>>(xcl, owA0, ob0, wA0, nullptr, nullptr, ycl);
    fused_deform<true><<<512, 512, 0, stream>>>(ycl, owA1, ob1, wA1, x, out, nullptr);
}

// Round 13
// 231.953 us; speedup vs baseline: 1.2033x; 1.2033x over previous
//
#include <hip/hip_runtime.h>
#include <hip/hip_bf16.h>

#define DEVI __device__ __forceinline__

constexpr int Bc = 2, Cc = 64, Tc = 4, Hc = 64, Wc = 64, OFFc = 54, KVc = 27;
constexpr int HW  = Hc * Wc;     // 4096
constexpr int THW = Tc * HW;     // 16384

typedef __attribute__((ext_vector_type(8))) short bf16x8;
typedef __attribute__((ext_vector_type(4))) float f32x4;

DEVI short f2bf(float f) {
    __hip_bfloat16 h = __float2bfloat16(f);
    return *reinterpret_cast<short*>(&h);
}
DEVI float bf2f(short s) {
    unsigned u = ((unsigned)(unsigned short)s) << 16;
    float f; __builtin_memcpy(&f, &u, 4); return f;
}

// ------- weights -> K-major MFMA A layout -------
__global__ __launch_bounds__(256) void w_prep(const float* __restrict__ w,
                                              __hip_bfloat16* __restrict__ wAk, int ovalid) {
    int i = blockIdx.x * 256 + threadIdx.x;   // 216*512 = 110592
    if (i >= 216 * 512) return;
    int u = i >> 9, r = i & 511;
    int mf = u & 3, ch = (u >> 2) & 1, tap = u >> 3;
    int o = mf * 16 + (r >> 5), c = ch * 32 + (r & 31);
    float v = (o < ovalid) ? w[(o * Cc + c) * KVc + tap] : 0.f;
    wAk[i] = __float2bfloat16(v);
}

// ------- cast + transpose to channel-last bf16 -------
__global__ __launch_bounds__(256) void cast_cl(const float* __restrict__ x,
                                               __hip_bfloat16* __restrict__ xcl) {
    __shared__ float s[64][65];
    int tid = threadIdx.x;
    int bi  = blockIdx.x;
    int h = bi & 63, t = (bi >> 6) & 3, b = bi >> 8;

    const float* xp = x + (size_t)b * Cc * THW + t * HW + h * 64;
    int w0 = tid & 63, c0 = tid >> 6;
    #pragma unroll
    for (int i = 0; i < 16; ++i) {
        int c = c0 + i * 4;
        s[c][w0] = xp[(size_t)c * THW + w0];
    }
    __syncthreads();

    __hip_bfloat16* dst = xcl + (((size_t)b * Tc + t) * HW + (size_t)h * 64) * 64;
    #pragma unroll
    for (int r = 0; r < 2; ++r) {
        int j  = tid + r * 256;
        int w  = j >> 3;
        int c8 = j & 7;
        bf16x8 v;
        #pragma unroll
        for (int jj = 0; jj < 8; ++jj)
            v[jj] = f2bf(s[c8 * 8 + jj][w]);
        *reinterpret_cast<bf16x8*>(dst + w * 64 + c8 * 8) = v;
    }
}

// ================= fused offset-conv + deformable-conv, LDS-staged, pipelined =================
// block = (b,t,h) full row, 512 thr = 8 waves = nf(4) x chh(2).
// __launch_bounds__(512,2): VGPR cap 128 (LDS caps at 2 blocks/CU anyway) so the
// depth-2 issue/consume pipeline buffers can actually live in registers — R10-R12
// were silently clamped to 64 VGPR which serialized every load (the ~110us wall).
// Plane->XCD: pid = blockIdx&7 (R10-validated ~11MB FETCH).
template <bool L2>
__global__ __launch_bounds__(512, 2) void fused_deform(
    const __hip_bfloat16* __restrict__ src, const __hip_bfloat16* __restrict__ owAk,
    const float* __restrict__ obias, const __hip_bfloat16* __restrict__ wAk,
    const float* __restrict__ xres, float* __restrict__ outf,
    __hip_bfloat16* __restrict__ ycl)
{
    __shared__ __align__(16) char s_mem[40960 + 14256];
    short* s_tile = (short*)s_mem;                 // [5][64 w][64 c] bf16, swizzled
    float* s_off  = (float*)(s_mem + 40960);       // [54][66]
    float* s_red  = (float*)s_mem;                 // aliased after pass B: [64][68]

    int tid = threadIdx.x;
    int wv = tid >> 6, lane = tid & 63, l15 = lane & 15, l4 = lane >> 4;
    int nf = wv & 3, chh = wv >> 2;
    int bi = blockIdx.x;
    int pid = bi & 7, h = bi >> 3;       // plane -> XCD via %8 round-robin
    int b = pid >> 2, t = pid & 3;

    int p = nf * 16 + l15;               // position (MFMA N index)
    int cbase = chh * 32 + l4 * 8;       // channel slice (MFMA K slice)
    int ktlo = (t == 0) ? 1 : 0, kthi = (t == 3) ? 2 : 3;

    for (int i = tid; i < OFFc * 66; i += 512) s_off[i] = obias[i / 66];

    const __hip_bfloat16* xb = src + ((size_t)b << 20);
    int wst = tid >> 3, sst = tid & 7;   // staging lane coords

    auto stage_load = [&](int kt, bf16x8 (&reg)[5]) {
        int tt = t + kt - 1;
        const __hip_bfloat16* xt = xb + ((size_t)tt << 18);
        #pragma unroll
        for (int r = 0; r < 5; ++r) {
            int hh = h - 2 + r;
            bf16x8 v = {0, 0, 0, 0, 0, 0, 0, 0};
            if ((unsigned)hh < 64u)
                v = *reinterpret_cast<const bf16x8*>(xt + ((hh * 64 + wst) << 6) + sst * 8);
            reg[r] = v;
        }
    };
    auto stage_write = [&](bf16x8 (&reg)[5]) {
        #pragma unroll
        for (int r = 0; r < 5; ++r) {
            int byte = (r * 8192 + wst * 128 + sst * 16) ^ ((wst & 7) << 4);
            *reinterpret_cast<bf16x8*>((char*)s_tile + byte) = reg[r];
        }
    };
    auto ldread = [&](int sl, int w) -> bf16x8 {
        int byte = (sl * 8192 + w * 128 + cbase * 2) ^ ((w & 7) << 4);
        return *reinterpret_cast<const bf16x8*>((const char*)s_tile + byte);
    };

    // ================= pass A: offset conv =================
    {
        f32x4 cacc[4];
        #pragma unroll
        for (int mf = 0; mf < 4; ++mf) cacc[mf] = (f32x4){0.f, 0.f, 0.f, 0.f};

        auto issueA = [&](int kt, int rr, bf16x8 &bv, bf16x8 (&af)[4]) {
            int kh = rr / 3, kw = rr % 3, tap = kt * 9 + rr;
            int ws = p + kw - 1;
            int wsc = min(max(ws, 0), 63);
            bv = ldread(kh + 1, wsc);
            if ((unsigned)ws >= 64u) bv = (bf16x8){0, 0, 0, 0, 0, 0, 0, 0};
            const __hip_bfloat16* ab = owAk + ((tap * 2 + chh) << 11) + (l15 << 5) + (l4 << 3);
            #pragma unroll
            for (int mf = 0; mf < 4; ++mf)
                af[mf] = *reinterpret_cast<const bf16x8*>(ab + (mf << 9));
        };
        auto consumeA = [&](bf16x8 &bv, bf16x8 (&af)[4]) {
            #pragma unroll
            for (int mf = 0; mf < 4; ++mf)
                cacc[mf] = __builtin_amdgcn_mfma_f32_16x16x32_bf16(af[mf], bv, cacc[mf], 0, 0, 0);
        };

        bf16x8 streg[5];
        stage_load(ktlo, streg);
        for (int kt = ktlo; kt < kthi; ++kt) {
            __syncthreads();
            stage_write(streg);
            __syncthreads();
            if (kt + 1 < kthi) stage_load(kt + 1, streg);

            bf16x8 bvA, bvB, afA[4], afB[4];
            issueA(kt, 0, bvA, afA);
            #pragma unroll
            for (int rr = 0; rr < 8; rr += 2) {
                issueA(kt, rr + 1, bvB, afB);
                consumeA(bvA, afA);
                if (rr + 2 < 9) issueA(kt, rr + 2, bvA, afA);
                consumeA(bvB, afB);
            }
            consumeA(bvA, afA);   // rr = 8
        }
        #pragma unroll
        for (int mf = 0; mf < 4; ++mf)
            #pragma unroll
            for (int jj = 0; jj < 4; ++jj) {
                int o = mf * 16 + l4 * 4 + jj;
                if (o < OFFc) atomicAdd(&s_off[o * 66 + p], cacc[mf][jj]);
            }
    }

    // ================= pass B: deformable conv =================
    f32x4 dacc[4];
    #pragma unroll
    for (int mf = 0; mf < 4; ++mf) dacc[mf] = (f32x4){0.f, 0.f, 0.f, 0.f};

    {
        auto issueB = [&](int kt, int rr, bf16x8 (&g)[4], bf16x8 (&af)[4], float (&cf)[4]) {
            int kh = rr / 3, kw = rr % 3, tap = kt * 9 + rr;
            int tt = t + kt - 1;
            const __hip_bfloat16* xt = xb + ((size_t)tt << 18);
            float dh = s_off[(tap * 2 + 0) * 66 + p];
            float dw = s_off[(tap * 2 + 1) * 66 + p];
            float hs  = (float)(h + kh - 1) + dh;
            float wsf = (float)(p + kw - 1) + dw;
            float fh = floorf(hs), fw = floorf(wsf);
            int h0 = (int)fh, w0 = (int)fw;
            float lh = hs - fh, lw = wsf - fw;
            float q0 = (1.f - lw) * (((unsigned)w0 < 64u) ? 1.f : 0.f);
            float q1 = lw         * (((unsigned)(w0 + 1) < 64u) ? 1.f : 0.f);
            int wc0 = min(max(w0, 0), 63), wc1 = min(max(w0 + 1, 0), 63);
            int r0 = h0 - (h - 2);
            int r0c = min(max(r0, 0), 3);
            g[0] = ldread(r0c, wc0);     g[1] = ldread(r0c, wc1);
            g[2] = ldread(r0c + 1, wc0); g[3] = ldread(r0c + 1, wc1);
            bool bad = (r0 < 0) | (r0 > 3);
            if (__any((int)bad)) {
                // exact global fallback (|dh| >= 1; ~never taken)
                float u0 = (1.f - lh) * (((unsigned)h0 < 64u) ? 1.f : 0.f);
                float u1 = lh         * (((unsigned)(h0 + 1) < 64u) ? 1.f : 0.f);
                cf[0] = u0 * q0; cf[1] = u0 * q1; cf[2] = u1 * q0; cf[3] = u1 * q1;
                int hc0 = min(max(h0, 0), 63), hc1 = min(max(h0 + 1, 0), 63);
                g[0] = *reinterpret_cast<const bf16x8*>(xt + ((hc0 * 64 + wc0) << 6) + cbase);
                g[1] = *reinterpret_cast<const bf16x8*>(xt + ((hc0 * 64 + wc1) << 6) + cbase);
                g[2] = *reinterpret_cast<const bf16x8*>(xt + ((hc1 * 64 + wc0) << 6) + cbase);
                g[3] = *reinterpret_cast<const bf16x8*>(xt + ((hc1 * 64 + wc1) << 6) + cbase);
            } else {
                cf[0] = (1.f - lh) * q0; cf[1] = (1.f - lh) * q1;
                cf[2] = lh * q0;         cf[3] = lh * q1;
            }
            const __hip_bfloat16* ab = wAk + ((tap * 2 + chh) << 11) + (l15 << 5) + (l4 << 3);
            #pragma unroll
            for (int mf = 0; mf < 4; ++mf)
                af[mf] = *reinterpret_cast<const bf16x8*>(ab + (mf << 9));
        };
        auto consumeB = [&](bf16x8 (&g)[4], bf16x8 (&af)[4], float (&cf)[4]) {
            bf16x8 bfrag;
            #pragma unroll
            for (int jj = 0; jj < 8; ++jj) {
                float s = cf[0] * bf2f(g[0][jj]) + cf[1] * bf2f(g[1][jj])
                        + cf[2] * bf2f(g[2][jj]) + cf[3] * bf2f(g[3][jj]);
                bfrag[jj] = f2bf(s);
            }
            #pragma unroll
            for (int mf = 0; mf < 4; ++mf)
                dacc[mf] = __builtin_amdgcn_mfma_f32_16x16x32_bf16(af[mf], bfrag, dacc[mf], 0, 0, 0);
        };

        bf16x8 streg[5];
        stage_load(ktlo, streg);
        for (int kt = ktlo; kt < kthi; ++kt) {
            __syncthreads();          // also guards s_off completeness on first iter
            stage_write(streg);
            __syncthreads();
            if (kt + 1 < kthi) stage_load(kt + 1, streg);

            bf16x8 gA[4], gB[4], afA[4], afB[4];
            float cA[4], cB[4];
            issueB(kt, 0, gA, afA, cA);
            #pragma unroll
            for (int rr = 0; rr < 8; rr += 2) {
                issueB(kt, rr + 1, gB, afB, cB);
                consumeB(gA, afA, cA);
                if (rr + 2 < 9) issueB(kt, rr + 2, gA, afA, cA);
                consumeB(gB, afB, cB);
            }
            consumeB(gA, afA, cA);    // rr = 8
        }
    }

    // ---- reduce: s_red aliased onto tile ----
    __syncthreads();
    for (int i = tid; i < 64 * 68; i += 512) s_red[i] = 0.f;
    __syncthreads();
    #pragma unroll
    for (int mf = 0; mf < 4; ++mf)
        #pragma unroll
        for (int jj = 0; jj < 4; ++jj) {
            int o = mf * 16 + l4 * 4 + jj;
            atomicAdd(&s_red[p * 68 + o], dacc[mf][jj]);
        }
    __syncthreads();

    // ---- fused epilogue ----
    if (!L2) {
        int pp = tid >> 3, o8 = (tid & 7) << 3;
        __hip_bfloat16* dst = ycl + ((((size_t)b * Tc + t) * HW + h * 64 + pp) << 6) + o8;
        bf16x8 o8v;
        #pragma unroll
        for (int jj = 0; jj < 8; ++jj) {
            float v = s_red[pp * 68 + o8 + jj];
            v = v >= 0.f ? v : 0.1f * v;
            o8v[jj] = f2bf(v);
        }
        *reinterpret_cast<bf16x8*>(dst) = o8v;
    } else {
        int o = tid >> 3, pg = (tid & 7) << 3;
        size_t base = ((size_t)(b * Cc + o) * Tc + t) * HW + h * 64 + pg;
        #pragma unroll
        for (int q = 0; q < 2; ++q) {
            f32x4 r, xv = *reinterpret_cast<const f32x4*>(xres + base + q * 4);
            #pragma unroll
            for (int jj = 0; jj < 4; ++jj) r[jj] = s_red[(pg + q * 4 + jj) * 68 + o] + xv[jj];
            *reinterpret_cast<f32x4*>(outf + base + q * 4) = r;
        }
    }
}

extern "C" void kernel_launch(void* const* d_in, const int* in_sizes, int n_in,
                              void* d_out, int out_size, void* d_ws, size_t ws_size,
                              hipStream_t stream)
{
    const float* x   = (const float*)d_in[0];
    const float* w0  = (const float*)d_in[1];
    const float* ow0 = (const float*)d_in[2];
    const float* ob0 = (const float*)d_in[3];
    const float* w1  = (const float*)d_in[4];
    const float* ow1 = (const float*)d_in[5];
    const float* ob1 = (const float*)d_in[6];
    float* out = (float*)d_out;

    __hip_bfloat16* xcl  = (__hip_bfloat16*)d_ws;
    __hip_bfloat16* ycl  = xcl  + (size_t)Bc * THW * 64;
    __hip_bfloat16* owA0 = ycl  + (size_t)Bc * THW * 64;
    __hip_bfloat16* owA1 = owA0 + (size_t)216 * 512;
    __hip_bfloat16* wA0  = owA1 + (size_t)216 * 512;
    __hip_bfloat16* wA1  = wA0  + (size_t)216 * 512;

    w_prep<<<432, 256, 0, stream>>>(ow0, owA0, OFFc);
    w_prep<<<432, 256, 0, stream>>>(ow1, owA1, OFFc);
    w_prep<<<432, 256, 0, stream>>>(w0,  wA0,  Cc);
    w_prep<<<432, 256, 0, stream>>>(w1,  wA1,  Cc);
    cast_cl<<<512, 256, 0, stream>>>(x, xcl);

    fused_deform<false><<<512, 512, 0, stream>>>(xcl, owA0, ob0, wA0, nullptr, nullptr, ycl);
    fused_deform<true><<<512, 512, 0, stream>>>(ycl, owA1, ob1, wA1, x, out, nullptr);
}

// Round 14
// 219.014 us; speedup vs baseline: 1.2744x; 1.0591x over previous
//
#include <hip/hip_runtime.h>
#include <hip/hip_bf16.h>

#define DEVI __device__ __forceinline__

constexpr int Bc = 2, Cc = 64, Tc = 4, Hc = 64, Wc = 64, OFFc = 54, KVc = 27;
constexpr int HW  = Hc * Wc;     // 4096
constexpr int THW = Tc * HW;     // 16384

typedef __attribute__((ext_vector_type(8))) short bf16x8;
typedef __attribute__((ext_vector_type(4))) float f32x4;

DEVI short f2bf(float f) {
    __hip_bfloat16 h = __float2bfloat16(f);
    return *reinterpret_cast<short*>(&h);
}
DEVI float bf2f(short s) {
    unsigned u = ((unsigned)(unsigned short)s) << 16;
    float f; __builtin_memcpy(&f, &u, 4); return f;
}

// ------- weights -> K-major MFMA A layout -------
__global__ __launch_bounds__(256) void w_prep(const float* __restrict__ w,
                                              __hip_bfloat16* __restrict__ wAk, int ovalid) {
    int i = blockIdx.x * 256 + threadIdx.x;   // 216*512 = 110592
    if (i >= 216 * 512) return;
    int u = i >> 9, r = i & 511;
    int mf = u & 3, ch = (u >> 2) & 1, tap = u >> 3;
    int o = mf * 16 + (r >> 5), c = ch * 32 + (r & 31);
    float v = (o < ovalid) ? w[(o * Cc + c) * KVc + tap] : 0.f;
    wAk[i] = __float2bfloat16(v);
}

// ------- cast + transpose to channel-last bf16 -------
__global__ __launch_bounds__(256) void cast_cl(const float* __restrict__ x,
                                               __hip_bfloat16* __restrict__ xcl) {
    __shared__ float s[64][65];
    int tid = threadIdx.x;
    int bi  = blockIdx.x;
    int h = bi & 63, t = (bi >> 6) & 3, b = bi >> 8;

    const float* xp = x + (size_t)b * Cc * THW + t * HW + h * 64;
    int w0 = tid & 63, c0 = tid >> 6;
    #pragma unroll
    for (int i = 0; i < 16; ++i) {
        int c = c0 + i * 4;
        s[c][w0] = xp[(size_t)c * THW + w0];
    }
    __syncthreads();

    __hip_bfloat16* dst = xcl + (((size_t)b * Tc + t) * HW + (size_t)h * 64) * 64;
    #pragma unroll
    for (int r = 0; r < 2; ++r) {
        int j  = tid + r * 256;
        int w  = j >> 3;
        int c8 = j & 7;
        bf16x8 v;
        #pragma unroll
        for (int jj = 0; jj < 8; ++jj)
            v[jj] = f2bf(s[c8 * 8 + jj][w]);
        *reinterpret_cast<bf16x8*>(dst + w * 64 + c8 * 8) = v;
    }
}

// ================= fused offset-conv + deformable-conv, LDS-staged, pipelined =================
// block = (b,t,h) full row, 512 thr = 8 waves = nf(4) x chh(2).
// KEY CHANGE vs R13: pass B main loop is BRANCH-FREE. The old in-loop global
// fallback merged global loads into the lerp's inputs, forcing vmcnt(0) every
// tap (drains af prefetch + staging = the ~110us wall). Now: always sample the
// clamped LDS window, record badmask, and run an exact delta-correction pass
// AFTER the loop (never taken for ~0.02-scale offsets; exec-masked when taken).
template <bool L2>
__global__ __launch_bounds__(512, 2) void fused_deform(
    const __hip_bfloat16* __restrict__ src, const __hip_bfloat16* __restrict__ owAk,
    const float* __restrict__ obias, const __hip_bfloat16* __restrict__ wAk,
    const float* __restrict__ xres, float* __restrict__ outf,
    __hip_bfloat16* __restrict__ ycl)
{
    __shared__ __align__(16) char s_mem[40960 + 14256];
    short* s_tile = (short*)s_mem;                 // [5][64 w][64 c] bf16, swizzled
    float* s_off  = (float*)(s_mem + 40960);       // [54][66]
    float* s_red  = (float*)s_mem;                 // aliased after pass B: [64][68]

    int tid = threadIdx.x;
    int wv = tid >> 6, lane = tid & 63, l15 = lane & 15, l4 = lane >> 4;
    int nf = wv & 3, chh = wv >> 2;
    int bi = blockIdx.x;
    int pid = bi & 7, h = bi >> 3;       // plane -> XCD via %8 round-robin
    int b = pid >> 2, t = pid & 3;

    int p = nf * 16 + l15;               // position (MFMA N index)
    int cbase = chh * 32 + l4 * 8;       // channel slice (MFMA K slice)
    int ktlo = (t == 0) ? 1 : 0, kthi = (t == 3) ? 2 : 3;

    for (int i = tid; i < OFFc * 66; i += 512) s_off[i] = obias[i / 66];

    const __hip_bfloat16* xb = src + ((size_t)b << 20);
    int wst = tid >> 3, sst = tid & 7;   // staging lane coords

    auto stage_load = [&](int kt, bf16x8 (&reg)[5]) {
        int tt = t + kt - 1;
        const __hip_bfloat16* xt = xb + ((size_t)tt << 18);
        #pragma unroll
        for (int r = 0; r < 5; ++r) {
            int hh = h - 2 + r;
            bf16x8 v = {0, 0, 0, 0, 0, 0, 0, 0};
            if ((unsigned)hh < 64u)
                v = *reinterpret_cast<const bf16x8*>(xt + ((hh * 64 + wst) << 6) + sst * 8);
            reg[r] = v;
        }
    };
    auto stage_write = [&](bf16x8 (&reg)[5]) {
        #pragma unroll
        for (int r = 0; r < 5; ++r) {
            int byte = (r * 8192 + wst * 128 + sst * 16) ^ ((wst & 7) << 4);
            *reinterpret_cast<bf16x8*>((char*)s_tile + byte) = reg[r];
        }
    };
    auto ldread = [&](int sl, int w) -> bf16x8 {
        int byte = (sl * 8192 + w * 128 + cbase * 2) ^ ((w & 7) << 4);
        return *reinterpret_cast<const bf16x8*>((const char*)s_tile + byte);
    };

    // ================= pass A: offset conv =================
    {
        f32x4 cacc[4];
        #pragma unroll
        for (int mf = 0; mf < 4; ++mf) cacc[mf] = (f32x4){0.f, 0.f, 0.f, 0.f};

        auto issueA = [&](int kt, int rr, bf16x8 &bv, bf16x8 (&af)[4]) {
            int kh = rr / 3, kw = rr % 3, tap = kt * 9 + rr;
            int ws = p + kw - 1;
            int wsc = min(max(ws, 0), 63);
            bv = ldread(kh + 1, wsc);
            if ((unsigned)ws >= 64u) bv = (bf16x8){0, 0, 0, 0, 0, 0, 0, 0};
            const __hip_bfloat16* ab = owAk + ((tap * 2 + chh) << 11) + (l15 << 5) + (l4 << 3);
            #pragma unroll
            for (int mf = 0; mf < 4; ++mf)
                af[mf] = *reinterpret_cast<const bf16x8*>(ab + (mf << 9));
        };
        auto consumeA = [&](bf16x8 &bv, bf16x8 (&af)[4]) {
            #pragma unroll
            for (int mf = 0; mf < 4; ++mf)
                cacc[mf] = __builtin_amdgcn_mfma_f32_16x16x32_bf16(af[mf], bv, cacc[mf], 0, 0, 0);
        };

        bf16x8 streg[5];
        stage_load(ktlo, streg);
        for (int kt = ktlo; kt < kthi; ++kt) {
            __syncthreads();
            stage_write(streg);
            __syncthreads();
            if (kt + 1 < kthi) stage_load(kt + 1, streg);

            bf16x8 bvA, bvB, afA[4], afB[4];
            issueA(kt, 0, bvA, afA);
            #pragma unroll
            for (int rr = 0; rr < 8; rr += 2) {
                issueA(kt, rr + 1, bvB, afB);
                consumeA(bvA, afA);
                if (rr + 2 < 9) issueA(kt, rr + 2, bvA, afA);
                consumeA(bvB, afB);
            }
            consumeA(bvA, afA);   // rr = 8
        }
        #pragma unroll
        for (int mf = 0; mf < 4; ++mf)
            #pragma unroll
            for (int jj = 0; jj < 4; ++jj) {
                int o = mf * 16 + l4 * 4 + jj;
                if (o < OFFc) atomicAdd(&s_off[o * 66 + p], cacc[mf][jj]);
            }
    }

    // ================= pass B: deformable conv (branch-free main loop) =================
    f32x4 dacc[4];
    #pragma unroll
    for (int mf = 0; mf < 4; ++mf) dacc[mf] = (f32x4){0.f, 0.f, 0.f, 0.f};

    unsigned badmask = 0;   // bit per tap: window miss (|dh| >= ~1); corrected after loop

    {
        auto issueB = [&](int kt, int rr, bf16x8 (&g)[4], bf16x8 (&af)[4], float (&cf)[4]) {
            int kh = rr / 3, kw = rr % 3, tap = kt * 9 + rr;
            float dh = s_off[(tap * 2 + 0) * 66 + p];
            float dw = s_off[(tap * 2 + 1) * 66 + p];
            float hs  = (float)(h + kh - 1) + dh;
            float wsf = (float)(p + kw - 1) + dw;
            float fh = floorf(hs), fw = floorf(wsf);
            int h0 = (int)fh, w0 = (int)fw;
            float lh = hs - fh, lw = wsf - fw;
            float q0 = (1.f - lw) * (((unsigned)w0 < 64u) ? 1.f : 0.f);
            float q1 = lw         * (((unsigned)(w0 + 1) < 64u) ? 1.f : 0.f);
            int wc0 = min(max(w0, 0), 63), wc1 = min(max(w0 + 1, 0), 63);
            int r0 = h0 - (h - 2);
            int r0c = min(max(r0, 0), 3);
            badmask |= ((r0 != r0c) ? 1u : 0u) << tap;
            g[0] = ldread(r0c, wc0);     g[1] = ldread(r0c, wc1);
            g[2] = ldread(r0c + 1, wc0); g[3] = ldread(r0c + 1, wc1);
            // window rows outside the image are zero-filled -> h-masks free
            cf[0] = (1.f - lh) * q0; cf[1] = (1.f - lh) * q1;
            cf[2] = lh * q0;         cf[3] = lh * q1;
            const __hip_bfloat16* ab = wAk + ((tap * 2 + chh) << 11) + (l15 << 5) + (l4 << 3);
            #pragma unroll
            for (int mf = 0; mf < 4; ++mf)
                af[mf] = *reinterpret_cast<const bf16x8*>(ab + (mf << 9));
        };
        auto consumeB = [&](bf16x8 (&g)[4], bf16x8 (&af)[4], float (&cf)[4]) {
            bf16x8 bfrag;
            #pragma unroll
            for (int jj = 0; jj < 8; ++jj) {
                float s = cf[0] * bf2f(g[0][jj]) + cf[1] * bf2f(g[1][jj])
                        + cf[2] * bf2f(g[2][jj]) + cf[3] * bf2f(g[3][jj]);
                bfrag[jj] = f2bf(s);
            }
            #pragma unroll
            for (int mf = 0; mf < 4; ++mf)
                dacc[mf] = __builtin_amdgcn_mfma_f32_16x16x32_bf16(af[mf], bfrag, dacc[mf], 0, 0, 0);
        };

        bf16x8 streg[5];
        stage_load(ktlo, streg);
        for (int kt = ktlo; kt < kthi; ++kt) {
            __syncthreads();          // also guards s_off completeness on first iter
            stage_write(streg);
            __syncthreads();
            if (kt + 1 < kthi) stage_load(kt + 1, streg);

            bf16x8 gA[4], gB[4], afA[4], afB[4];
            float cA[4], cB[4];
            issueB(kt, 0, gA, afA, cA);
            #pragma unroll
            for (int rr = 0; rr < 8; rr += 2) {
                issueB(kt, rr + 1, gB, afB, cB);
                consumeB(gA, afA, cA);
                if (rr + 2 < 9) issueB(kt, rr + 2, gA, afA, cA);
                consumeB(gB, afB, cB);
            }
            consumeB(gA, afA, cA);    // rr = 8
        }
    }

    // ---- exact correction for window misses (never taken for small offsets) ----
    if (__any((int)(badmask != 0u))) {
        for (int kt = ktlo; kt < kthi; ++kt) {
            int tt = t + kt - 1;
            const __hip_bfloat16* xt = xb + ((size_t)tt << 18);
            for (int rr = 0; rr < 9; ++rr) {
                int tap = kt * 9 + rr;
                if (!__any((int)((badmask >> tap) & 1u))) continue;
                int kh = rr / 3, kw = rr % 3;
                float dh = s_off[(tap * 2 + 0) * 66 + p];
                float dw = s_off[(tap * 2 + 1) * 66 + p];
                float hs  = (float)(h + kh - 1) + dh;
                float wsf = (float)(p + kw - 1) + dw;
                float fh = floorf(hs), fw = floorf(wsf);
                int h0 = (int)fh, w0 = (int)fw;
                float lh = hs - fh, lw = wsf - fw;
                float q0 = (1.f - lw) * (((unsigned)w0 < 64u) ? 1.f : 0.f);
                float q1 = lw         * (((unsigned)(w0 + 1) < 64u) ? 1.f : 0.f);
                int wc0 = min(max(w0, 0), 63), wc1 = min(max(w0 + 1, 0), 63);
                int r0 = h0 - (h - 2);
                int r0c = min(max(r0, 0), 3);
                bool bad = ((badmask >> tap) & 1u) != 0u;
                // true sample (h-masked, clamped)
                float u0 = (1.f - lh) * (((unsigned)h0 < 64u) ? 1.f : 0.f);
                float u1 = lh         * (((unsigned)(h0 + 1) < 64u) ? 1.f : 0.f);
                int hc0 = min(max(h0, 0), 63), hc1 = min(max(h0 + 1, 0), 63);
                bf16x8 tg0 = *reinterpret_cast<const bf16x8*>(xt + ((hc0 * 64 + wc0) << 6) + cbase);
                bf16x8 tg1 = *reinterpret_cast<const bf16x8*>(xt + ((hc0 * 64 + wc1) << 6) + cbase);
                bf16x8 tg2 = *reinterpret_cast<const bf16x8*>(xt + ((hc1 * 64 + wc0) << 6) + cbase);
                bf16x8 tg3 = *reinterpret_cast<const bf16x8*>(xt + ((hc1 * 64 + wc1) << 6) + cbase);
                // approx sample as main loop computed it (clamped window rows, zero-fill)
                int ra0 = h - 2 + r0c, ra1 = ra0 + 1;
                float m0 = ((unsigned)ra0 < 64u) ? 1.f : 0.f;
                float m1 = ((unsigned)ra1 < 64u) ? 1.f : 0.f;
                int rc0 = min(max(ra0, 0), 63), rc1 = min(max(ra1, 0), 63);
                bf16x8 ag0 = *reinterpret_cast<const bf16x8*>(xt + ((rc0 * 64 + wc0) << 6) + cbase);
                bf16x8 ag1 = *reinterpret_cast<const bf16x8*>(xt + ((rc0 * 64 + wc1) << 6) + cbase);
                bf16x8 ag2 = *reinterpret_cast<const bf16x8*>(xt + ((rc1 * 64 + wc0) << 6) + cbase);
                bf16x8 ag3 = *reinterpret_cast<const bf16x8*>(xt + ((rc1 * 64 + wc1) << 6) + cbase);
                bf16x8 bfrag;
                #pragma unroll
                for (int jj = 0; jj < 8; ++jj) {
                    float ft = u0 * (q0 * bf2f(tg0[jj]) + q1 * bf2f(tg1[jj]))
                             + u1 * (q0 * bf2f(tg2[jj]) + q1 * bf2f(tg3[jj]));
                    float fa = (1.f - lh) * m0 * (q0 * bf2f(ag0[jj]) + q1 * bf2f(ag1[jj]))
                             + lh * m1 * (q0 * bf2f(ag2[jj]) + q1 * bf2f(ag3[jj]));
                    bfrag[jj] = f2bf(bad ? (ft - fa) : 0.f);
                }
                const __hip_bfloat16* ab = wAk + ((tap * 2 + chh) << 11) + (l15 << 5) + (l4 << 3);
                #pragma unroll
                for (int mf = 0; mf < 4; ++mf) {
                    bf16x8 af = *reinterpret_cast<const bf16x8*>(ab + (mf << 9));
                    dacc[mf] = __builtin_amdgcn_mfma_f32_16x16x32_bf16(af, bfrag, dacc[mf], 0, 0, 0);
                }
            }
        }
    }

    // ---- reduce: s_red aliased onto tile ----
    __syncthreads();
    for (int i = tid; i < 64 * 68; i += 512) s_red[i] = 0.f;
    __syncthreads();
    #pragma unroll
    for (int mf = 0; mf < 4; ++mf)
        #pragma unroll
        for (int jj = 0; jj < 4; ++jj) {
            int o = mf * 16 + l4 * 4 + jj;
            atomicAdd(&s_red[p * 68 + o], dacc[mf][jj]);
        }
    __syncthreads();

    // ---- fused epilogue ----
    if (!L2) {
        int pp = tid >> 3, o8 = (tid & 7) << 3;
        __hip_bfloat16* dst = ycl + ((((size_t)b * Tc + t) * HW + h * 64 + pp) << 6) + o8;
        bf16x8 o8v;
        #pragma unroll
        for (int jj = 0; jj < 8; ++jj) {
            float v = s_red[pp * 68 + o8 + jj];
            v = v >= 0.f ? v : 0.1f * v;
            o8v[jj] = f2bf(v);
        }
        *reinterpret_cast<bf16x8*>(dst) = o8v;
    } else {
        int o = tid >> 3, pg = (tid & 7) << 3;
        size_t base = ((size_t)(b * Cc + o) * Tc + t) * HW + h * 64 + pg;
        #pragma unroll
        for (int q = 0; q < 2; ++q) {
            f32x4 r, xv = *reinterpret_cast<const f32x4*>(xres + base + q * 4);
            #pragma unroll
            for (int jj = 0; jj < 4; ++jj) r[jj] = s_red[(pg + q * 4 + jj) * 68 + o] + xv[jj];
            *reinterpret_cast<f32x4*>(outf + base + q * 4) = r;
        }
    }
}

extern "C" void kernel_launch(void* const* d_in, const int* in_sizes, int n_in,
                              void* d_out, int out_size, void* d_ws, size_t ws_size,
                              hipStream_t stream)
{
    const float* x   = (const float*)d_in[0];
    const float* w0  = (const float*)d_in[1];
    const float* ow0 = (const float*)d_in[2];
    const float* ob0 = (const float*)d_in[3];
    const float* w1  = (const float*)d_in[4];
    const float* ow1 = (const float*)d_in[5];
    const float* ob1 = (const float*)d_in[6];
    float* out = (float*)d_out;

    __hip_bfloat16* xcl  = (__hip_bfloat16*)d_ws;
    __hip_bfloat16* ycl  = xcl  + (size_t)Bc * THW * 64;
    __hip_bfloat16* owA0 = ycl  + (size_t)Bc * THW * 64;
    __hip_bfloat16* owA1 = owA0 + (size_t)216 * 512;
    __hip_bfloat16* wA0  = owA1 + (size_t)216 * 512;
    __hip_bfloat16* wA1  = wA0  + (size_t)216 * 512;

    w_prep<<<432, 256, 0, stream>>>(ow0, owA0, OFFc);
    w_prep<<<432, 256, 0, stream>>>(ow1, owA1, OFFc);
    w_prep<<<432, 256, 0, stream>>>(w0,  wA0,  Cc);
    w_prep<<<432, 256, 0, stream>>>(w1,  wA1,  Cc);
    cast_cl<<<512, 256, 0, stream>>>(x, xcl);

    fused_deform<false><<<512, 512, 0, stream>>>(xcl, owA0, ob0, wA0, nullptr, nullptr, ycl);
    fused_deform<true><<<512, 512, 0, stream>>>(ycl, owA1, ob1, wA1, x, out, nullptr);
}

// Round 15
// 207.359 us; speedup vs baseline: 1.3460x; 1.0562x over previous
//
#include <hip/hip_runtime.h>
#include <hip/hip_bf16.h>

#define DEVI __device__ __forceinline__

constexpr int Bc = 2, Cc = 64, Tc = 4, Hc = 64, Wc = 64, OFFc = 54, KVc = 27;
constexpr int HW  = Hc * Wc;     // 4096
constexpr int THW = Tc * HW;     // 16384

typedef __attribute__((ext_vector_type(8))) short bf16x8;
typedef __attribute__((ext_vector_type(4))) float f32x4;

DEVI short f2bf(float f) {
    __hip_bfloat16 h = __float2bfloat16(f);
    return *reinterpret_cast<short*>(&h);
}
DEVI float bf2f(short s) {
    unsigned u = ((unsigned)(unsigned short)s) << 16;
    float f; __builtin_memcpy(&f, &u, 4); return f;
}

// ------- weights -> K-major MFMA A layout -------
__global__ __launch_bounds__(256) void w_prep(const float* __restrict__ w,
                                              __hip_bfloat16* __restrict__ wAk, int ovalid) {
    int i = blockIdx.x * 256 + threadIdx.x;   // 216*512 = 110592
    if (i >= 216 * 512) return;
    int u = i >> 9, r = i & 511;
    int mf = u & 3, ch = (u >> 2) & 1, tap = u >> 3;
    int o = mf * 16 + (r >> 5), c = ch * 32 + (r & 31);
    float v = (o < ovalid) ? w[(o * Cc + c) * KVc + tap] : 0.f;
    wAk[i] = __float2bfloat16(v);
}

// ------- cast + transpose to channel-last bf16 -------
__global__ __launch_bounds__(256) void cast_cl(const float* __restrict__ x,
                                               __hip_bfloat16* __restrict__ xcl) {
    __shared__ float s[64][65];
    int tid = threadIdx.x;
    int bi  = blockIdx.x;
    int h = bi & 63, t = (bi >> 6) & 3, b = bi >> 8;

    const float* xp = x + (size_t)b * Cc * THW + t * HW + h * 64;
    int w0 = tid & 63, c0 = tid >> 6;
    #pragma unroll
    for (int i = 0; i < 16; ++i) {
        int c = c0 + i * 4;
        s[c][w0] = xp[(size_t)c * THW + w0];
    }
    __syncthreads();

    __hip_bfloat16* dst = xcl + (((size_t)b * Tc + t) * HW + (size_t)h * 64) * 64;
    #pragma unroll
    for (int r = 0; r < 2; ++r) {
        int j  = tid + r * 256;
        int w  = j >> 3;
        int c8 = j & 7;
        bf16x8 v;
        #pragma unroll
        for (int jj = 0; jj < 8; ++jj)
            v[jj] = f2bf(s[c8 * 8 + jj][w]);
        *reinterpret_cast<bf16x8*>(dst + w * 64 + c8 * 8) = v;
    }
}

// ================= fused offset-conv + deformable-conv, small-block edition =================
// block = (b,t,h,whalf): 32 positions, 256 thr = 4 waves = nf(2 pos-groups) x chh(2 ch-halves).
// 1024 blocks -> 4 INDEPENDENT blocks/CU (16 waves/CU from different blocks): latency is
// hidden by cross-block TLP, not source pipelining (which hipcc defeats / spills).
// LDS: tile [5 rows][40 wcols][64 ch] bf16 swizzled (25.6KB) + s_off (7.2KB) = 33KB.
// Branch-free pass B + exact post-loop badmask correction (R14-proven).
// Plane->XCD: pid = blockIdx&7 (R10-validated ~11MB FETCH).
constexpr int WT = 40;            // tile w-columns, covers global w in [wb-3, wb+36]
constexpr int RSTRIDE = WT * 128; // 5120 bytes per tile row

template <bool L2>
__global__ __launch_bounds__(256, 4) void fused_deform(
    const __hip_bfloat16* __restrict__ src, const __hip_bfloat16* __restrict__ owAk,
    const float* __restrict__ obias, const __hip_bfloat16* __restrict__ wAk,
    const float* __restrict__ xres, float* __restrict__ outf,
    __hip_bfloat16* __restrict__ ycl)
{
    __shared__ __align__(16) char s_mem[5 * RSTRIDE + 7344];
    short* s_tile = (short*)s_mem;                    // swizzled tile
    float* s_off  = (float*)(s_mem + 5 * RSTRIDE);    // [27][2][34]
    float* s_red  = (float*)s_mem;                    // aliased after pass B: [32][68]

    int tid = threadIdx.x;
    int wv = tid >> 6, lane = tid & 63, l15 = lane & 15, l4 = lane >> 4;
    int nf = wv & 1, chh = wv >> 1;
    int bi = blockIdx.x;
    int pid = bi & 7, j = bi >> 3;        // plane -> XCD via %8 round-robin
    int whalf = j & 1, h = j >> 1;
    int b = pid >> 2, t = pid & 3;
    int wb = whalf * 32;

    int pl = nf * 16 + l15;               // local position 0..31
    int p  = wb + pl;                     // global w position
    int cbase = chh * 32 + l4 * 8;        // channel slice (MFMA K slice)
    int ktlo = (t == 0) ? 1 : 0, kthi = (t == 3) ? 2 : 3;

    // init s_off with bias (pad cols 32,33 junk; never read)
    for (int i = tid; i < KVc * 2 * 34; i += 256) {
        int k = i / 68, rem = i - k * 68, jo = rem / 34;
        ((float*)s_off)[i] = obias[2 * k + jo];
    }

    const __hip_bfloat16* xb = src + ((size_t)b << 20);

    auto stage = [&](int kt) {
        int tt = t + kt - 1;   // valid by loop range
        const __hip_bfloat16* xt = xb + ((size_t)tt << 18);
        for (int i = tid; i < 5 * WT * 8; i += 256) {
            int r = i / (WT * 8), v = i - r * (WT * 8);
            int wl = v >> 3, ss = v & 7;
            int hh = h - 2 + r;
            int wg = wb - 3 + wl;
            bf16x8 val = {0, 0, 0, 0, 0, 0, 0, 0};
            if ((unsigned)hh < 64u && (unsigned)wg < 64u)
                val = *reinterpret_cast<const bf16x8*>(xt + ((hh * 64 + wg) << 6) + ss * 8);
            int byte = (r * RSTRIDE + wl * 128 + ss * 16) ^ ((wl & 7) << 4);
            *reinterpret_cast<bf16x8*>((char*)s_tile + byte) = val;
        }
    };
    auto ldread = [&](int sl, int wg) -> bf16x8 {   // wg = clamped global w (in window)
        int wl = wg - (wb - 3);
        int byte = (sl * RSTRIDE + wl * 128 + cbase * 2) ^ ((wl & 7) << 4);
        return *reinterpret_cast<const bf16x8*>((const char*)s_tile + byte);
    };

    // ================= pass A: offset conv =================
    f32x4 cacc[4];
    #pragma unroll
    for (int mf = 0; mf < 4; ++mf) cacc[mf] = (f32x4){0.f, 0.f, 0.f, 0.f};

    for (int kt = ktlo; kt < kthi; ++kt) {
        __syncthreads();
        stage(kt);
        __syncthreads();
        #pragma unroll
        for (int rr = 0; rr < 9; ++rr) {
            int kh = rr / 3, kw = rr % 3, tap = kt * 9 + rr;
            int ws = p + kw - 1;
            int wsc = min(max(ws, 0), 63);
            bf16x8 bv = ldread(kh + 1, wsc);
            if ((unsigned)ws >= 64u) bv = (bf16x8){0, 0, 0, 0, 0, 0, 0, 0};
            const __hip_bfloat16* ab = owAk + ((tap * 2 + chh) << 11) + (l15 << 5) + (l4 << 3);
            #pragma unroll
            for (int mf = 0; mf < 4; ++mf) {
                bf16x8 af = *reinterpret_cast<const bf16x8*>(ab + (mf << 9));
                cacc[mf] = __builtin_amdgcn_mfma_f32_16x16x32_bf16(af, bv, cacc[mf], 0, 0, 0);
            }
        }
    }
    #pragma unroll
    for (int mf = 0; mf < 4; ++mf)
        #pragma unroll
        for (int jj = 0; jj < 4; ++jj) {
            int o = mf * 16 + l4 * 4 + jj;
            if (o < OFFc) atomicAdd(&s_off[(o >> 1) * 68 + (o & 1) * 34 + pl], cacc[mf][jj]);
        }

    // ================= pass B: deformable conv (branch-free) =================
    f32x4 dacc[4];
    #pragma unroll
    for (int mf = 0; mf < 4; ++mf) dacc[mf] = (f32x4){0.f, 0.f, 0.f, 0.f};

    unsigned badmask = 0;

    for (int kt = ktlo; kt < kthi; ++kt) {
        __syncthreads();     // also guards s_off completeness on first iter
        stage(kt);
        __syncthreads();
        #pragma unroll
        for (int rr = 0; rr < 9; ++rr) {
            int kh = rr / 3, kw = rr % 3, tap = kt * 9 + rr;
            float dh = s_off[tap * 68 + pl];
            float dw = s_off[tap * 68 + 34 + pl];
            float hs  = (float)(h + kh - 1) + dh;
            float wsf = (float)(p + kw - 1) + dw;
            float fh = floorf(hs), fw = floorf(wsf);
            int h0 = (int)fh, w0 = (int)fw;
            float lh = hs - fh, lw = wsf - fw;
            float q0 = (1.f - lw) * (((unsigned)w0 < 64u) ? 1.f : 0.f);
            float q1 = lw         * (((unsigned)(w0 + 1) < 64u) ? 1.f : 0.f);
            int wc0 = min(max(w0, 0), 63), wc1 = min(max(w0 + 1, 0), 63);
            int r0 = h0 - (h - 2);
            int r0c = min(max(r0, 0), 3);
            badmask |= ((r0 != r0c) ? 1u : 0u) << tap;
            bf16x8 g0 = ldread(r0c, wc0),     g1 = ldread(r0c, wc1);
            bf16x8 g2 = ldread(r0c + 1, wc0), g3 = ldread(r0c + 1, wc1);
            float cf0 = (1.f - lh) * q0, cf1 = (1.f - lh) * q1;
            float cf2 = lh * q0,         cf3 = lh * q1;
            bf16x8 bfrag;
            #pragma unroll
            for (int jj = 0; jj < 8; ++jj) {
                float s = cf0 * bf2f(g0[jj]) + cf1 * bf2f(g1[jj])
                        + cf2 * bf2f(g2[jj]) + cf3 * bf2f(g3[jj]);
                bfrag[jj] = f2bf(s);
            }
            const __hip_bfloat16* ab = wAk + ((tap * 2 + chh) << 11) + (l15 << 5) + (l4 << 3);
            #pragma unroll
            for (int mf = 0; mf < 4; ++mf) {
                bf16x8 af = *reinterpret_cast<const bf16x8*>(ab + (mf << 9));
                dacc[mf] = __builtin_amdgcn_mfma_f32_16x16x32_bf16(af, bfrag, dacc[mf], 0, 0, 0);
            }
        }
    }

    // ---- exact correction for window misses (never taken for ~0.02-scale offsets) ----
    if (__any((int)(badmask != 0u))) {
        for (int kt = ktlo; kt < kthi; ++kt) {
            int tt = t + kt - 1;
            const __hip_bfloat16* xt = xb + ((size_t)tt << 18);
            for (int rr = 0; rr < 9; ++rr) {
                int tap = kt * 9 + rr;
                if (!__any((int)((badmask >> tap) & 1u))) continue;
                int kh = rr / 3, kw = rr % 3;
                float dh = s_off[tap * 68 + pl];
                float dw = s_off[tap * 68 + 34 + pl];
                float hs  = (float)(h + kh - 1) + dh;
                float wsf = (float)(p + kw - 1) + dw;
                float fh = floorf(hs), fw = floorf(wsf);
                int h0 = (int)fh, w0 = (int)fw;
                float lh = hs - fh, lw = wsf - fw;
                float q0 = (1.f - lw) * (((unsigned)w0 < 64u) ? 1.f : 0.f);
                float q1 = lw         * (((unsigned)(w0 + 1) < 64u) ? 1.f : 0.f);
                int wc0 = min(max(w0, 0), 63), wc1 = min(max(w0 + 1, 0), 63);
                int r0 = h0 - (h - 2);
                int r0c = min(max(r0, 0), 3);
                bool bad = ((badmask >> tap) & 1u) != 0u;
                float u0 = (1.f - lh) * (((unsigned)h0 < 64u) ? 1.f : 0.f);
                float u1 = lh         * (((unsigned)(h0 + 1) < 64u) ? 1.f : 0.f);
                int hc0 = min(max(h0, 0), 63), hc1 = min(max(h0 + 1, 0), 63);
                bf16x8 tg0 = *reinterpret_cast<const bf16x8*>(xt + ((hc0 * 64 + wc0) << 6) + cbase);
                bf16x8 tg1 = *reinterpret_cast<const bf16x8*>(xt + ((hc0 * 64 + wc1) << 6) + cbase);
                bf16x8 tg2 = *reinterpret_cast<const bf16x8*>(xt + ((hc1 * 64 + wc0) << 6) + cbase);
                bf16x8 tg3 = *reinterpret_cast<const bf16x8*>(xt + ((hc1 * 64 + wc1) << 6) + cbase);
                int ra0 = h - 2 + r0c, ra1 = ra0 + 1;
                float m0 = ((unsigned)ra0 < 64u) ? 1.f : 0.f;
                float m1 = ((unsigned)ra1 < 64u) ? 1.f : 0.f;
                int rc0 = min(max(ra0, 0), 63), rc1 = min(max(ra1, 0), 63);
                bf16x8 ag0 = *reinterpret_cast<const bf16x8*>(xt + ((rc0 * 64 + wc0) << 6) + cbase);
                bf16x8 ag1 = *reinterpret_cast<const bf16x8*>(xt + ((rc0 * 64 + wc1) << 6) + cbase);
                bf16x8 ag2 = *reinterpret_cast<const bf16x8*>(xt + ((rc1 * 64 + wc0) << 6) + cbase);
                bf16x8 ag3 = *reinterpret_cast<const bf16x8*>(xt + ((rc1 * 64 + wc1) << 6) + cbase);
                bf16x8 bfrag;
                #pragma unroll
                for (int jj = 0; jj < 8; ++jj) {
                    float ft = u0 * (q0 * bf2f(tg0[jj]) + q1 * bf2f(tg1[jj]))
                             + u1 * (q0 * bf2f(tg2[jj]) + q1 * bf2f(tg3[jj]));
                    float fa = (1.f - lh) * m0 * (q0 * bf2f(ag0[jj]) + q1 * bf2f(ag1[jj]))
                             + lh * m1 * (q0 * bf2f(ag2[jj]) + q1 * bf2f(ag3[jj]));
                    bfrag[jj] = f2bf(bad ? (ft - fa) : 0.f);
                }
                const __hip_bfloat16* ab = wAk + ((tap * 2 + chh) << 11) + (l15 << 5) + (l4 << 3);
                #pragma unroll
                for (int mf = 0; mf < 4; ++mf) {
                    bf16x8 af = *reinterpret_cast<const bf16x8*>(ab + (mf << 9));
                    dacc[mf] = __builtin_amdgcn_mfma_f32_16x16x32_bf16(af, bfrag, dacc[mf], 0, 0, 0);
                }
            }
        }
    }

    // ---- reduce: s_red aliased onto tile ----
    __syncthreads();
    for (int i = tid; i < 32 * 68; i += 256) s_red[i] = 0.f;
    __syncthreads();
    #pragma unroll
    for (int mf = 0; mf < 4; ++mf)
        #pragma unroll
        for (int jj = 0; jj < 4; ++jj) {
            int o = mf * 16 + l4 * 4 + jj;
            atomicAdd(&s_red[pl * 68 + o], dacc[mf][jj]);
        }
    __syncthreads();

    // ---- fused epilogue ----
    if (!L2) {
        // leaky-relu + channel-last bf16 store (32 pos x 64 ch)
        int pp = tid >> 3, o8 = (tid & 7) << 3;
        __hip_bfloat16* dst = ycl + ((((size_t)b * Tc + t) * HW + h * 64 + wb + pp) << 6) + o8;
        bf16x8 o8v;
        #pragma unroll
        for (int jj = 0; jj < 8; ++jj) {
            float v = s_red[pp * 68 + o8 + jj];
            v = v >= 0.f ? v : 0.1f * v;
            o8v[jj] = f2bf(v);
        }
        *reinterpret_cast<bf16x8*>(dst) = o8v;
    } else {
        // residual add + fp32 channel-first store
        int o = tid >> 2, pg = (tid & 3) << 3;
        size_t base = ((size_t)(b * Cc + o) * Tc + t) * HW + h * 64 + wb + pg;
        #pragma unroll
        for (int q = 0; q < 2; ++q) {
            f32x4 r, xv = *reinterpret_cast<const f32x4*>(xres + base + q * 4);
            #pragma unroll
            for (int jj = 0; jj < 4; ++jj) r[jj] = s_red[(pg + q * 4 + jj) * 68 + o] + xv[jj];
            *reinterpret_cast<f32x4*>(outf + base + q * 4) = r;
        }
    }
}

extern "C" void kernel_launch(void* const* d_in, const int* in_sizes, int n_in,
                              void* d_out, int out_size, void* d_ws, size_t ws_size,
                              hipStream_t stream)
{
    const float* x   = (const float*)d_in[0];
    const float* w0  = (const float*)d_in[1];
    const float* ow0 = (const float*)d_in[2];
    const float* ob0 = (const float*)d_in[3];
    const float* w1  = (const float*)d_in[4];
    const float* ow1 = (const float*)d_in[5];
    const float* ob1 = (const float*)d_in[6];
    float* out = (float*)d_out;

    __hip_bfloat16* xcl  = (__hip_bfloat16*)d_ws;
    __hip_bfloat16* ycl  = xcl  + (size_t)Bc * THW * 64;
    __hip_bfloat16* owA0 = ycl  + (size_t)Bc * THW * 64;
    __hip_bfloat16* owA1 = owA0 + (size_t)216 * 512;
    __hip_bfloat16* wA0  = owA1 + (size_t)216 * 512;
    __hip_bfloat16* wA1  = wA0  + (size_t)216 * 512;

    w_prep<<<432, 256, 0, stream>>>(ow0, owA0, OFFc);
    w_prep<<<432, 256, 0, stream>>>(ow1, owA1, OFFc);
    w_prep<<<432, 256, 0, stream>>>(w0,  wA0,  Cc);
    w_prep<<<432, 256, 0, stream>>>(w1,  wA1,  Cc);
    cast_cl<<<512, 256, 0, stream>>>(x, xcl);

    fused_deform<false><<<1024, 256, 0, stream>>>(xcl, owA0, ob0, wA0, nullptr, nullptr, ycl);
    fused_deform<true><<<1024, 256, 0, stream>>>(ycl, owA1, ob1, wA1, x, out, nullptr);
}